// Round 1
// baseline (2975.205 us; speedup 1.0000x reference)
//
#include <hip/hip_runtime.h>
#include <math.h>

#define N_NODES 50000
#define N_EDGES 800000
#define NUM_GRAPHS_ 128

__device__ __forceinline__ float elu_f(float v) {
    return v > 0.f ? v : (__expf(v) - 1.f);
}

// ---------------------------------------------------------------------------
// ew[e] = edge_attr[e,:16] . w_fc1 + b_fc1 ; c[dst[e]] += ew[e]
// ---------------------------------------------------------------------------
__global__ void ew_kernel(const float* __restrict__ edge_attr,
                          const float* __restrict__ w_fc1,
                          const float* __restrict__ b_fc1,
                          const int* __restrict__ edge_index,
                          float* __restrict__ ew, float* __restrict__ c) {
    int e = blockIdx.x * blockDim.x + threadIdx.x;
    if (e >= N_EDGES) return;
    const float4* ea = (const float4*)(edge_attr + (size_t)e * 16);
    const float4* wf = (const float4*)w_fc1;
    float acc = b_fc1[0];
#pragma unroll
    for (int i = 0; i < 4; i++) {
        float4 a = ea[i], w = wf[i];
        acc += a.x * w.x + a.y * w.y + a.z * w.z + a.w * w.w;
    }
    ew[e] = acc;
    int dst = edge_index[N_EDGES + e];
    unsafeAtomicAdd(&c[dst], acc);
}

// ---------------------------------------------------------------------------
// s[dst[e], :] += ew[e] * x[src[e], :]   (DIN = 64 or 128, float4 per thread)
// ---------------------------------------------------------------------------
template <int DIN>
__global__ void scatter_kernel(const float* __restrict__ x,
                               const int* __restrict__ edge_index,
                               const float* __restrict__ ew,
                               float* __restrict__ s) {
    constexpr int VPE = DIN / 4;  // float4 groups per edge (pow2)
    int gid = blockIdx.x * blockDim.x + threadIdx.x;
    int e = gid / VPE;
    if (e >= N_EDGES) return;
    int d = gid & (VPE - 1);
    int src = edge_index[e];
    int dst = edge_index[N_EDGES + e];
    float w = ew[e];
    float4 v = ((const float4*)(x + (size_t)src * DIN))[d];
    float* outp = s + (size_t)dst * DIN + d * 4;
    unsafeAtomicAdd(outp + 0, w * v.x);
    unsafeAtomicAdd(outp + 1, w * v.y);
    unsafeAtomicAdd(outp + 2, w * v.z);
    unsafeAtomicAdd(outp + 3, w * v.w);
}

// ---------------------------------------------------------------------------
// xout = elu( [x | s | c*x] @ [w3 ; w1 ; -w2] + b3 + c*b1 )
// Tiles: BM=64 rows x BN=64 cols, BK=16, 256 threads, 4x4 regs/thread.
// ---------------------------------------------------------------------------
template <int DIN, int DOUT>
__global__ __launch_bounds__(256) void leconv_gemm(
    const float* __restrict__ xin, const float* __restrict__ s,
    const float* __restrict__ c,
    const float* __restrict__ w1, const float* __restrict__ b1,
    const float* __restrict__ w2, const float* __restrict__ w3,
    const float* __restrict__ b3, float* __restrict__ xout) {
    constexpr int K = 3 * DIN;
    constexpr int BM = 64, BN = 64, BK = 16;
    __shared__ float As[BK][BM];
    __shared__ float Bs[BK][BN];
    const int tid = threadIdx.x;
    const int row0 = blockIdx.x * BM;
    const int col0 = blockIdx.y * BN;

    // A staging: thread -> (row am, k-group akg), one float4 along k
    const int am = tid >> 2;      // 0..63
    const int akg = tid & 3;      // 0..3
    // B staging: thread -> (k bk, col-group bcg), one float4 along cols
    const int bk = tid >> 4;      // 0..15
    const int bcg = tid & 15;     // 0..15
    // compute mapping: 16x16 threads, 4 rows x 4 cols each
    const int tm = tid >> 4;      // 0..15
    const int tn = tid & 15;      // 0..15

    const int arow = row0 + am;
    const bool arow_ok = arow < N_NODES;
    const float crow_a = arow_ok ? c[arow] : 0.f;

    float acc[4][4] = {};

    for (int k0 = 0; k0 < K; k0 += BK) {
        const int region = k0 / DIN;  // whole BK chunk lies in one region (DIN%BK==0)
        // ---- load A frag to regs
        float4 av = make_float4(0.f, 0.f, 0.f, 0.f);
        if (arow_ok) {
            const int koff = k0 - region * DIN + akg * 4;
            const float* srcp = (region == 1) ? (s + (size_t)arow * DIN + koff)
                                              : (xin + (size_t)arow * DIN + koff);
            av = *(const float4*)srcp;
            if (region == 2) {
                av.x *= crow_a; av.y *= crow_a; av.z *= crow_a; av.w *= crow_a;
            }
        }
        // ---- load B frag to regs
        const int kboff = (k0 - region * DIN) + bk;
        const float* wsrc = (region == 0) ? w3 : (region == 1 ? w1 : w2);
        float4 bv = *(const float4*)(wsrc + (size_t)kboff * DOUT + col0 + bcg * 4);
        if (region == 2) { bv.x = -bv.x; bv.y = -bv.y; bv.z = -bv.z; bv.w = -bv.w; }

        __syncthreads();  // previous tile consumed
        As[akg * 4 + 0][am] = av.x;
        As[akg * 4 + 1][am] = av.y;
        As[akg * 4 + 2][am] = av.z;
        As[akg * 4 + 3][am] = av.w;
        *(float4*)&Bs[bk][bcg * 4] = bv;
        __syncthreads();

#pragma unroll
        for (int kk = 0; kk < BK; kk++) {
            float4 a4 = *(const float4*)&As[kk][tm * 4];
            float4 b4 = *(const float4*)&Bs[kk][tn * 4];
            float ar[4] = {a4.x, a4.y, a4.z, a4.w};
            float br[4] = {b4.x, b4.y, b4.z, b4.w};
#pragma unroll
            for (int i = 0; i < 4; i++)
#pragma unroll
                for (int j = 0; j < 4; j++) acc[i][j] += ar[i] * br[j];
        }
    }

    // ---- epilogue: + b3 + c*b1, ELU, store
#pragma unroll
    for (int i = 0; i < 4; i++) {
        const int row = row0 + tm * 4 + i;
        if (row >= N_NODES) break;
        const float cr = c[row];
        const int col = col0 + tn * 4;
        float4 o;
        o.x = elu_f(acc[i][0] + b3[col + 0] + cr * b1[col + 0]);
        o.y = elu_f(acc[i][1] + b3[col + 1] + cr * b1[col + 1]);
        o.z = elu_f(acc[i][2] + b3[col + 2] + cr * b1[col + 2]);
        o.w = elu_f(acc[i][3] + b3[col + 3] + cr * b1[col + 3]);
        *(float4*)(xout + (size_t)row * DOUT + col) = o;
    }
}

// ---------------------------------------------------------------------------
// out[g, :] = max over nodes of graph g of h[:, :64]; batch is sorted.
// ---------------------------------------------------------------------------
__global__ void pool_kernel(const float* __restrict__ h,
                            const int* __restrict__ batch,
                            float* __restrict__ out) {
    const int g = blockIdx.x;
    const int tid = threadIdx.x;
    // lower_bound for g and g+1 (redundant per-thread, cheap)
    int lo = 0, hi = N_NODES;
    while (lo < hi) { int mid = (lo + hi) >> 1; if (batch[mid] < g) lo = mid + 1; else hi = mid; }
    const int beg = lo;
    lo = beg; hi = N_NODES;
    while (lo < hi) { int mid = (lo + hi) >> 1; if (batch[mid] < g + 1) lo = mid + 1; else hi = mid; }
    const int end = lo;

    __shared__ float red[256];
    const int col = tid & 63;
    const int rg = tid >> 6;  // 0..3
    float m = -3.0e38f;
    for (int r = beg + rg; r < end; r += 4) m = fmaxf(m, h[(size_t)r * 64 + col]);
    red[tid] = m;
    __syncthreads();
    if (tid < 64) {
        m = fmaxf(fmaxf(red[tid], red[tid + 64]), fmaxf(red[tid + 128], red[tid + 192]));
        out[g * 64 + tid] = m;
    }
}

extern "C" void kernel_launch(void* const* d_in, const int* in_sizes, int n_in,
                              void* d_out, int out_size, void* d_ws, size_t ws_size,
                              hipStream_t stream) {
    const float* x = (const float*)d_in[0];
    const int* ei = (const int*)d_in[1];
    const float* ea = (const float*)d_in[2];
    const int* batch = (const int*)d_in[3];
    const float* wfc = (const float*)d_in[4];
    const float* bfc = (const float*)d_in[5];
    const float* w1_0 = (const float*)d_in[6];
    const float* b1_0 = (const float*)d_in[7];
    const float* w2_0 = (const float*)d_in[8];
    const float* w3_0 = (const float*)d_in[9];
    const float* b3_0 = (const float*)d_in[10];
    const float* w1_1 = (const float*)d_in[11];
    const float* b1_1 = (const float*)d_in[12];
    const float* w2_1 = (const float*)d_in[13];
    const float* w3_1 = (const float*)d_in[14];
    const float* b3_1 = (const float*)d_in[15];
    const float* w1_2 = (const float*)d_in[16];
    const float* b1_2 = (const float*)d_in[17];
    const float* w2_2 = (const float*)d_in[18];
    const float* w3_2 = (const float*)d_in[19];
    const float* b3_2 = (const float*)d_in[20];
    float* out = (float*)d_out;

    char* ws = (char*)d_ws;
    float* ew = (float*)(ws);                  // E floats        (3.2 MB)
    float* c  = (float*)(ws + 3200000);        // N floats        (0.2 MB)
    float* s  = (float*)(ws + 3400000);        // N*128 floats    (25.6 MB)
    float* hA = (float*)(ws + 29000000);       // N*64 floats     (12.8 MB)
    float* hB = (float*)(ws + 41800000);       // N*128 floats    (25.6 MB)

    hipMemsetAsync(c, 0, N_NODES * sizeof(float), stream);
    ew_kernel<<<(N_EDGES + 255) / 256, 256, 0, stream>>>(ea, wfc, bfc, ei, ew, c);

    dim3 g64((N_NODES + 63) / 64, 1);
    dim3 g128((N_NODES + 63) / 64, 2);

    // layer 0: 64 -> 64, in x, out hA
    hipMemsetAsync(s, 0, (size_t)N_NODES * 64 * sizeof(float), stream);
    scatter_kernel<64><<<(N_EDGES * 16 + 255) / 256, 256, 0, stream>>>(x, ei, ew, s);
    leconv_gemm<64, 64><<<g64, 256, 0, stream>>>(x, s, c, w1_0, b1_0, w2_0, w3_0, b3_0, hA);

    // layer 1: 64 -> 128, in hA, out hB
    hipMemsetAsync(s, 0, (size_t)N_NODES * 64 * sizeof(float), stream);
    scatter_kernel<64><<<(N_EDGES * 16 + 255) / 256, 256, 0, stream>>>(hA, ei, ew, s);
    leconv_gemm<64, 128><<<g128, 256, 0, stream>>>(hA, s, c, w1_1, b1_1, w2_1, w3_1, b3_1, hB);

    // layer 2: 128 -> 64, in hB, out hA
    hipMemsetAsync(s, 0, (size_t)N_NODES * 128 * sizeof(float), stream);
    scatter_kernel<128><<<(N_EDGES * 32 + 255) / 256, 256, 0, stream>>>(hB, ei, ew, s);
    leconv_gemm<128, 64><<<g64, 256, 0, stream>>>(hB, s, c, w1_2, b1_2, w2_2, w3_2, b3_2, hA);

    // global max pool
    pool_kernel<<<NUM_GRAPHS_, 256, 0, stream>>>(hA, batch, out);
}

// Round 2
// 646.156 us; speedup vs baseline: 4.6045x; 4.6045x over previous
//
#include <hip/hip_runtime.h>
#include <math.h>

#define N_NODES 50000
#define N_EDGES 800000
#define NUM_GRAPHS_ 128

__device__ __forceinline__ float elu_f(float v) {
    return v > 0.f ? v : (__expf(v) - 1.f);
}

// ---------------------------------------------------------------------------
// ew[e] = edge_attr[e,:16] . w_fc1 + b_fc1 ;  c[dst] += ew ;  deg[dst] += 1
// ---------------------------------------------------------------------------
__global__ void ew_deg_kernel(const float* __restrict__ edge_attr,
                              const float* __restrict__ w_fc1,
                              const float* __restrict__ b_fc1,
                              const int* __restrict__ edge_index,
                              float* __restrict__ ew, float* __restrict__ c,
                              int* __restrict__ deg) {
    int e = blockIdx.x * blockDim.x + threadIdx.x;
    if (e >= N_EDGES) return;
    const float4* ea = (const float4*)(edge_attr + (size_t)e * 16);
    const float4* wf = (const float4*)w_fc1;
    float acc = b_fc1[0];
#pragma unroll
    for (int i = 0; i < 4; i++) {
        float4 a = ea[i], w = wf[i];
        acc += a.x * w.x + a.y * w.y + a.z * w.z + a.w * w.w;
    }
    ew[e] = acc;
    int dst = edge_index[N_EDGES + e];
    unsafeAtomicAdd(&c[dst], acc);
    atomicAdd(&deg[dst], 1);
}

// ---------------------------------------------------------------------------
// Single-block exclusive scan of deg[N] -> rowptr[N+1], cursor[N]
// ---------------------------------------------------------------------------
__global__ __launch_bounds__(256) void scan_kernel(const int* __restrict__ deg,
                                                   int* __restrict__ rowptr,
                                                   int* __restrict__ cursor) {
    __shared__ int partx[257];
    const int t = threadIdx.x;
    const int CH = (N_NODES + 255) / 256;  // 196
    const int beg = t * CH;
    const int end = min(beg + CH, N_NODES);
    int sum = 0;
    for (int i = beg; i < end; i++) sum += deg[i];
    __shared__ int part[256];
    part[t] = sum;
    __syncthreads();
    if (t == 0) {
        int run = 0;
        for (int i = 0; i < 256; i++) { partx[i] = run; run += part[i]; }
        partx[256] = run;
    }
    __syncthreads();
    int run = partx[t];
    for (int i = beg; i < end; i++) {
        rowptr[i] = run;
        cursor[i] = run;
        run += deg[i];
    }
    if (t == 255) rowptr[N_NODES] = partx[256];
}

// ---------------------------------------------------------------------------
// CSR placement: pos = cursor[dst]++ ; csr_src[pos]=src ; csr_w[pos]=ew[e]
// ---------------------------------------------------------------------------
__global__ void place_kernel(const int* __restrict__ edge_index,
                             const float* __restrict__ ew,
                             int* __restrict__ cursor,
                             int* __restrict__ csr_src,
                             float* __restrict__ csr_w) {
    int e = blockIdx.x * blockDim.x + threadIdx.x;
    if (e >= N_EDGES) return;
    int dst = edge_index[N_EDGES + e];
    int pos = atomicAdd(&cursor[dst], 1);
    csr_src[pos] = edge_index[e];
    csr_w[pos] = ew[e];
}

// ---------------------------------------------------------------------------
// Gather aggregation: s[i,:] = sum_{p in [rowptr[i],rowptr[i+1])} w_p * x[src_p,:]
// TPN = DIN/4 threads per node, float4 per thread. No atomics.
// ---------------------------------------------------------------------------
template <int DIN>
__global__ __launch_bounds__(256) void gather_kernel(
    const float* __restrict__ x, const int* __restrict__ rowptr,
    const int* __restrict__ csr_src, const float* __restrict__ csr_w,
    float* __restrict__ s) {
    constexpr int TPN = DIN / 4;
    const int gid = blockIdx.x * 256 + threadIdx.x;
    const int node = gid / TPN;
    if (node >= N_NODES) return;
    const int cg = gid & (TPN - 1);
    const int beg = rowptr[node];
    const int end = rowptr[node + 1];
    const float4* x4 = (const float4*)x;
    float4 acc = make_float4(0.f, 0.f, 0.f, 0.f);
    for (int p = beg; p < end; ++p) {
        const int src = csr_src[p];
        const float w = csr_w[p];
        float4 v = x4[(size_t)src * TPN + cg];
        acc.x += w * v.x; acc.y += w * v.y; acc.z += w * v.z; acc.w += w * v.w;
    }
    ((float4*)s)[(size_t)node * TPN + cg] = acc;
}

// ---------------------------------------------------------------------------
// xout = elu( [x | s | c*x] @ [w3 ; w1 ; -w2] + b3 + c*b1 )
// Tiles: BM=64 rows x BN=64 cols, BK=16, 256 threads, 4x4 regs/thread.
// ---------------------------------------------------------------------------
template <int DIN, int DOUT>
__global__ __launch_bounds__(256) void leconv_gemm(
    const float* __restrict__ xin, const float* __restrict__ s,
    const float* __restrict__ c,
    const float* __restrict__ w1, const float* __restrict__ b1,
    const float* __restrict__ w2, const float* __restrict__ w3,
    const float* __restrict__ b3, float* __restrict__ xout) {
    constexpr int K = 3 * DIN;
    constexpr int BM = 64, BN = 64, BK = 16;
    __shared__ float As[BK][BM];
    __shared__ float Bs[BK][BN];
    const int tid = threadIdx.x;
    const int row0 = blockIdx.x * BM;
    const int col0 = blockIdx.y * BN;

    const int am = tid >> 2;      // 0..63
    const int akg = tid & 3;      // 0..3
    const int bk = tid >> 4;      // 0..15
    const int bcg = tid & 15;     // 0..15
    const int tm = tid >> 4;      // 0..15
    const int tn = tid & 15;      // 0..15

    const int arow = row0 + am;
    const bool arow_ok = arow < N_NODES;
    const float crow_a = arow_ok ? c[arow] : 0.f;

    float acc[4][4] = {};

    for (int k0 = 0; k0 < K; k0 += BK) {
        const int region = k0 / DIN;
        float4 av = make_float4(0.f, 0.f, 0.f, 0.f);
        if (arow_ok) {
            const int koff = k0 - region * DIN + akg * 4;
            const float* srcp = (region == 1) ? (s + (size_t)arow * DIN + koff)
                                              : (xin + (size_t)arow * DIN + koff);
            av = *(const float4*)srcp;
            if (region == 2) {
                av.x *= crow_a; av.y *= crow_a; av.z *= crow_a; av.w *= crow_a;
            }
        }
        const int kboff = (k0 - region * DIN) + bk;
        const float* wsrc = (region == 0) ? w3 : (region == 1 ? w1 : w2);
        float4 bv = *(const float4*)(wsrc + (size_t)kboff * DOUT + col0 + bcg * 4);
        if (region == 2) { bv.x = -bv.x; bv.y = -bv.y; bv.z = -bv.z; bv.w = -bv.w; }

        __syncthreads();
        As[akg * 4 + 0][am] = av.x;
        As[akg * 4 + 1][am] = av.y;
        As[akg * 4 + 2][am] = av.z;
        As[akg * 4 + 3][am] = av.w;
        *(float4*)&Bs[bk][bcg * 4] = bv;
        __syncthreads();

#pragma unroll
        for (int kk = 0; kk < BK; kk++) {
            float4 a4 = *(const float4*)&As[kk][tm * 4];
            float4 b4 = *(const float4*)&Bs[kk][tn * 4];
            float ar[4] = {a4.x, a4.y, a4.z, a4.w};
            float br[4] = {b4.x, b4.y, b4.z, b4.w};
#pragma unroll
            for (int i = 0; i < 4; i++)
#pragma unroll
                for (int j = 0; j < 4; j++) acc[i][j] += ar[i] * br[j];
        }
    }

#pragma unroll
    for (int i = 0; i < 4; i++) {
        const int row = row0 + tm * 4 + i;
        if (row >= N_NODES) break;
        const float cr = c[row];
        const int col = col0 + tn * 4;
        float4 o;
        o.x = elu_f(acc[i][0] + b3[col + 0] + cr * b1[col + 0]);
        o.y = elu_f(acc[i][1] + b3[col + 1] + cr * b1[col + 1]);
        o.z = elu_f(acc[i][2] + b3[col + 2] + cr * b1[col + 2]);
        o.w = elu_f(acc[i][3] + b3[col + 3] + cr * b1[col + 3]);
        *(float4*)(xout + (size_t)row * DOUT + col) = o;
    }
}

// ---------------------------------------------------------------------------
// out[g, :] = max over nodes of graph g of h[:, :64]; batch is sorted.
// ---------------------------------------------------------------------------
__global__ void pool_kernel(const float* __restrict__ h,
                            const int* __restrict__ batch,
                            float* __restrict__ out) {
    const int g = blockIdx.x;
    const int tid = threadIdx.x;
    int lo = 0, hi = N_NODES;
    while (lo < hi) { int mid = (lo + hi) >> 1; if (batch[mid] < g) lo = mid + 1; else hi = mid; }
    const int beg = lo;
    lo = beg; hi = N_NODES;
    while (lo < hi) { int mid = (lo + hi) >> 1; if (batch[mid] < g + 1) lo = mid + 1; else hi = mid; }
    const int end = lo;

    __shared__ float red[256];
    const int col = tid & 63;
    const int rg = tid >> 6;  // 0..3
    float m = -3.0e38f;
    for (int r = beg + rg; r < end; r += 4) m = fmaxf(m, h[(size_t)r * 64 + col]);
    red[tid] = m;
    __syncthreads();
    if (tid < 64) {
        m = fmaxf(fmaxf(red[tid], red[tid + 64]), fmaxf(red[tid + 128], red[tid + 192]));
        out[g * 64 + tid] = m;
    }
}

extern "C" void kernel_launch(void* const* d_in, const int* in_sizes, int n_in,
                              void* d_out, int out_size, void* d_ws, size_t ws_size,
                              hipStream_t stream) {
    const float* x = (const float*)d_in[0];
    const int* ei = (const int*)d_in[1];
    const float* ea = (const float*)d_in[2];
    const int* batch = (const int*)d_in[3];
    const float* wfc = (const float*)d_in[4];
    const float* bfc = (const float*)d_in[5];
    const float* w1_0 = (const float*)d_in[6];
    const float* b1_0 = (const float*)d_in[7];
    const float* w2_0 = (const float*)d_in[8];
    const float* w3_0 = (const float*)d_in[9];
    const float* b3_0 = (const float*)d_in[10];
    const float* w1_1 = (const float*)d_in[11];
    const float* b1_1 = (const float*)d_in[12];
    const float* w2_1 = (const float*)d_in[13];
    const float* w3_1 = (const float*)d_in[14];
    const float* b3_1 = (const float*)d_in[15];
    const float* w1_2 = (const float*)d_in[16];
    const float* b1_2 = (const float*)d_in[17];
    const float* w2_2 = (const float*)d_in[18];
    const float* w3_2 = (const float*)d_in[19];
    const float* b3_2 = (const float*)d_in[20];
    float* out = (float*)d_out;

    char* ws = (char*)d_ws;
    float* ew      = (float*)(ws);                 // E floats   (3.2 MB)
    float* c       = (float*)(ws + 3200000);       // N floats
    int*   deg     = (int*)  (ws + 3400000);       // N ints
    int*   cursor  = (int*)  (ws + 3600000);       // N ints
    int*   rowptr  = (int*)  (ws + 3800000);       // N+1 ints
    int*   csr_src = (int*)  (ws + 4000128);       // E ints     (3.2 MB)
    float* csr_w   = (float*)(ws + 7200128);       // E floats   (3.2 MB)
    float* s       = (float*)(ws + 10400128);      // N*128 floats (25.6 MB)
    float* hA      = (float*)(ws + 36000128);      // N*64 floats  (12.8 MB)
    float* hB      = (float*)(ws + 48800128);      // N*128 floats (25.6 MB)

    hipMemsetAsync(c, 0, N_NODES * sizeof(float), stream);
    hipMemsetAsync(deg, 0, N_NODES * sizeof(int), stream);

    ew_deg_kernel<<<(N_EDGES + 255) / 256, 256, 0, stream>>>(ea, wfc, bfc, ei, ew, c, deg);
    scan_kernel<<<1, 256, 0, stream>>>(deg, rowptr, cursor);
    place_kernel<<<(N_EDGES + 255) / 256, 256, 0, stream>>>(ei, ew, cursor, csr_src, csr_w);

    dim3 g64((N_NODES + 63) / 64, 1);
    dim3 g128((N_NODES + 63) / 64, 2);

    // layer 0: 64 -> 64, in x, out hA
    gather_kernel<64><<<(N_NODES * 16 + 255) / 256, 256, 0, stream>>>(x, rowptr, csr_src, csr_w, s);
    leconv_gemm<64, 64><<<g64, 256, 0, stream>>>(x, s, c, w1_0, b1_0, w2_0, w3_0, b3_0, hA);

    // layer 1: 64 -> 128, in hA, out hB
    gather_kernel<64><<<(N_NODES * 16 + 255) / 256, 256, 0, stream>>>(hA, rowptr, csr_src, csr_w, s);
    leconv_gemm<64, 128><<<g128, 256, 0, stream>>>(hA, s, c, w1_1, b1_1, w2_1, w3_1, b3_1, hB);

    // layer 2: 128 -> 64, in hB, out hA
    gather_kernel<128><<<(N_NODES * 32 + 255) / 256, 256, 0, stream>>>(hB, rowptr, csr_src, csr_w, s);
    leconv_gemm<128, 64><<<g64, 256, 0, stream>>>(hB, s, c, w1_2, b1_2, w2_2, w3_2, b3_2, hA);

    // global max pool
    pool_kernel<<<NUM_GRAPHS_, 256, 0, stream>>>(hA, batch, out);
}

// Round 3
// 533.452 us; speedup vs baseline: 5.5773x; 1.2113x over previous
//
#include <hip/hip_runtime.h>
#include <math.h>

#define N_NODES 50000
#define N_EDGES 800000
#define NUM_GRAPHS_ 128
#define SCAN_NB 98  // ceil(50000/512)

__device__ __forceinline__ float elu_f(float v) {
    return v > 0.f ? v : (__expf(v) - 1.f);
}

// ---------------------------------------------------------------------------
// ew[e] = edge_attr[e,:16] . w_fc1 + b_fc1 ;  c[dst] += ew ;  deg[dst] += 1
// ---------------------------------------------------------------------------
__global__ void ew_deg_kernel(const float* __restrict__ edge_attr,
                              const float* __restrict__ w_fc1,
                              const float* __restrict__ b_fc1,
                              const int* __restrict__ edge_index,
                              float* __restrict__ ew, float* __restrict__ c,
                              int* __restrict__ deg) {
    int e = blockIdx.x * blockDim.x + threadIdx.x;
    if (e >= N_EDGES) return;
    const float4* ea = (const float4*)(edge_attr + (size_t)e * 16);
    const float4* wf = (const float4*)w_fc1;
    float acc = b_fc1[0];
#pragma unroll
    for (int i = 0; i < 4; i++) {
        float4 a = ea[i], w = wf[i];
        acc += a.x * w.x + a.y * w.y + a.z * w.z + a.w * w.w;
    }
    ew[e] = acc;
    int dst = edge_index[N_EDGES + e];
    unsafeAtomicAdd(&c[dst], acc);
    atomicAdd(&deg[dst], 1);
}

// ---------------------------------------------------------------------------
// Hierarchical exclusive scan of deg[N] -> rowptr[N+1], cursor[N]
// scan1: per-block (512 elems) local scan + block sums
// ---------------------------------------------------------------------------
__global__ __launch_bounds__(256) void scan1_kernel(const int* __restrict__ deg,
                                                    int* __restrict__ rowptr,
                                                    int* __restrict__ blk_sums) {
    __shared__ int sh[256];
    const int t = threadIdx.x;
    const int base = blockIdx.x * 512;
    const int i0 = base + 2 * t, i1 = i0 + 1;
    const int d0 = (i0 < N_NODES) ? deg[i0] : 0;
    const int d1 = (i1 < N_NODES) ? deg[i1] : 0;
    const int pair = d0 + d1;
    int v = pair;
    sh[t] = v;
    __syncthreads();
#pragma unroll
    for (int off = 1; off < 256; off <<= 1) {
        int add = (t >= off) ? sh[t - off] : 0;
        __syncthreads();
        v += add;
        sh[t] = v;
        __syncthreads();
    }
    const int excl = v - pair;
    if (i0 < N_NODES) rowptr[i0] = excl;
    if (i1 < N_NODES) rowptr[i1] = excl + d0;
    if (t == 255) blk_sums[blockIdx.x] = v;
}

// scan2: scan the 98 block sums (single tiny block), write grand total
__global__ __launch_bounds__(128) void scan2_kernel(const int* __restrict__ blk_sums,
                                                    int* __restrict__ blk_offs,
                                                    int* __restrict__ rowptr) {
    __shared__ int sh[128];
    const int t = threadIdx.x;
    const int orig = (t < SCAN_NB) ? blk_sums[t] : 0;
    int v = orig;
    sh[t] = v;
    __syncthreads();
#pragma unroll
    for (int off = 1; off < 128; off <<= 1) {
        int add = (t >= off) ? sh[t - off] : 0;
        __syncthreads();
        v += add;
        sh[t] = v;
        __syncthreads();
    }
    if (t < SCAN_NB) blk_offs[t] = v - orig;
    if (t == 127) rowptr[N_NODES] = v;
}

// scan3: add block offsets in place, emit cursor
__global__ void scan3_kernel(int* __restrict__ rowptr,
                             const int* __restrict__ blk_offs,
                             int* __restrict__ cursor) {
    int i = blockIdx.x * blockDim.x + threadIdx.x;
    if (i >= N_NODES) return;
    int r = rowptr[i] + blk_offs[i >> 9];
    rowptr[i] = r;
    cursor[i] = r;
}

// ---------------------------------------------------------------------------
// CSR placement: pos = cursor[dst]++ ; csr_src[pos]=src ; csr_w[pos]=ew[e]
// ---------------------------------------------------------------------------
__global__ void place_kernel(const int* __restrict__ edge_index,
                             const float* __restrict__ ew,
                             int* __restrict__ cursor,
                             int* __restrict__ csr_src,
                             float* __restrict__ csr_w) {
    int e = blockIdx.x * blockDim.x + threadIdx.x;
    if (e >= N_EDGES) return;
    int dst = edge_index[N_EDGES + e];
    int pos = atomicAdd(&cursor[dst], 1);
    csr_src[pos] = edge_index[e];
    csr_w[pos] = ew[e];
}

// ---------------------------------------------------------------------------
// Gather aggregation: s[i,:] = sum_{p in row(i)} w_p * x[src_p,:]
// TPN = DIN/4 threads per node, float4 per thread. No atomics.
// ---------------------------------------------------------------------------
template <int DIN>
__global__ __launch_bounds__(256) void gather_kernel(
    const float* __restrict__ x, const int* __restrict__ rowptr,
    const int* __restrict__ csr_src, const float* __restrict__ csr_w,
    float* __restrict__ s) {
    constexpr int TPN = DIN / 4;
    const int gid = blockIdx.x * 256 + threadIdx.x;
    const int node = gid / TPN;
    if (node >= N_NODES) return;
    const int cg = gid & (TPN - 1);
    const int beg = rowptr[node];
    const int end = rowptr[node + 1];
    const float4* x4 = (const float4*)x;
    float4 acc = make_float4(0.f, 0.f, 0.f, 0.f);
    for (int p = beg; p < end; ++p) {
        const int src = csr_src[p];
        const float w = csr_w[p];
        float4 v = x4[(size_t)src * TPN + cg];
        acc.x += w * v.x; acc.y += w * v.y; acc.z += w * v.z; acc.w += w * v.w;
    }
    ((float4*)s)[(size_t)node * TPN + cg] = acc;
}

// ---------------------------------------------------------------------------
// xout = elu( [x | s | c*x] @ [w3 ; w1 ; -w2] + b3 + c*b1 )
// ---------------------------------------------------------------------------
template <int DIN, int DOUT>
__global__ __launch_bounds__(256) void leconv_gemm(
    const float* __restrict__ xin, const float* __restrict__ s,
    const float* __restrict__ c,
    const float* __restrict__ w1, const float* __restrict__ b1,
    const float* __restrict__ w2, const float* __restrict__ w3,
    const float* __restrict__ b3, float* __restrict__ xout) {
    constexpr int K = 3 * DIN;
    constexpr int BM = 64, BN = 64, BK = 16;
    __shared__ float As[BK][BM];
    __shared__ float Bs[BK][BN];
    const int tid = threadIdx.x;
    const int row0 = blockIdx.x * BM;
    const int col0 = blockIdx.y * BN;

    const int am = tid >> 2;      // 0..63
    const int akg = tid & 3;      // 0..3
    const int bk = tid >> 4;      // 0..15
    const int bcg = tid & 15;     // 0..15
    const int tm = tid >> 4;      // 0..15
    const int tn = tid & 15;      // 0..15

    const int arow = row0 + am;
    const bool arow_ok = arow < N_NODES;
    const float crow_a = arow_ok ? c[arow] : 0.f;

    float acc[4][4] = {};

    for (int k0 = 0; k0 < K; k0 += BK) {
        const int region = k0 / DIN;
        float4 av = make_float4(0.f, 0.f, 0.f, 0.f);
        if (arow_ok) {
            const int koff = k0 - region * DIN + akg * 4;
            const float* srcp = (region == 1) ? (s + (size_t)arow * DIN + koff)
                                              : (xin + (size_t)arow * DIN + koff);
            av = *(const float4*)srcp;
            if (region == 2) {
                av.x *= crow_a; av.y *= crow_a; av.z *= crow_a; av.w *= crow_a;
            }
        }
        const int kboff = (k0 - region * DIN) + bk;
        const float* wsrc = (region == 0) ? w3 : (region == 1 ? w1 : w2);
        float4 bv = *(const float4*)(wsrc + (size_t)kboff * DOUT + col0 + bcg * 4);
        if (region == 2) { bv.x = -bv.x; bv.y = -bv.y; bv.z = -bv.z; bv.w = -bv.w; }

        __syncthreads();
        As[akg * 4 + 0][am] = av.x;
        As[akg * 4 + 1][am] = av.y;
        As[akg * 4 + 2][am] = av.z;
        As[akg * 4 + 3][am] = av.w;
        *(float4*)&Bs[bk][bcg * 4] = bv;
        __syncthreads();

#pragma unroll
        for (int kk = 0; kk < BK; kk++) {
            float4 a4 = *(const float4*)&As[kk][tm * 4];
            float4 b4 = *(const float4*)&Bs[kk][tn * 4];
            float ar[4] = {a4.x, a4.y, a4.z, a4.w};
            float br[4] = {b4.x, b4.y, b4.z, b4.w};
#pragma unroll
            for (int i = 0; i < 4; i++)
#pragma unroll
                for (int j = 0; j < 4; j++) acc[i][j] += ar[i] * br[j];
        }
    }

#pragma unroll
    for (int i = 0; i < 4; i++) {
        const int row = row0 + tm * 4 + i;
        if (row >= N_NODES) break;
        const float cr = c[row];
        const int col = col0 + tn * 4;
        float4 o;
        o.x = elu_f(acc[i][0] + b3[col + 0] + cr * b1[col + 0]);
        o.y = elu_f(acc[i][1] + b3[col + 1] + cr * b1[col + 1]);
        o.z = elu_f(acc[i][2] + b3[col + 2] + cr * b1[col + 2]);
        o.w = elu_f(acc[i][3] + b3[col + 3] + cr * b1[col + 3]);
        *(float4*)(xout + (size_t)row * DOUT + col) = o;
    }
}

// ---------------------------------------------------------------------------
// out[g, :] = max over nodes of graph g of h[:, :64]; batch is sorted.
// ---------------------------------------------------------------------------
__global__ void pool_kernel(const float* __restrict__ h,
                            const int* __restrict__ batch,
                            float* __restrict__ out) {
    const int g = blockIdx.x;
    const int tid = threadIdx.x;
    int lo = 0, hi = N_NODES;
    while (lo < hi) { int mid = (lo + hi) >> 1; if (batch[mid] < g) lo = mid + 1; else hi = mid; }
    const int beg = lo;
    lo = beg; hi = N_NODES;
    while (lo < hi) { int mid = (lo + hi) >> 1; if (batch[mid] < g + 1) lo = mid + 1; else hi = mid; }
    const int end = lo;

    __shared__ float red[256];
    const int col = tid & 63;
    const int rg = tid >> 6;
    float m = -3.0e38f;
    for (int r = beg + rg; r < end; r += 4) m = fmaxf(m, h[(size_t)r * 64 + col]);
    red[tid] = m;
    __syncthreads();
    if (tid < 64) {
        m = fmaxf(fmaxf(red[tid], red[tid + 64]), fmaxf(red[tid + 128], red[tid + 192]));
        out[g * 64 + tid] = m;
    }
}

extern "C" void kernel_launch(void* const* d_in, const int* in_sizes, int n_in,
                              void* d_out, int out_size, void* d_ws, size_t ws_size,
                              hipStream_t stream) {
    const float* x = (const float*)d_in[0];
    const int* ei = (const int*)d_in[1];
    const float* ea = (const float*)d_in[2];
    const int* batch = (const int*)d_in[3];
    const float* wfc = (const float*)d_in[4];
    const float* bfc = (const float*)d_in[5];
    const float* w1_0 = (const float*)d_in[6];
    const float* b1_0 = (const float*)d_in[7];
    const float* w2_0 = (const float*)d_in[8];
    const float* w3_0 = (const float*)d_in[9];
    const float* b3_0 = (const float*)d_in[10];
    const float* w1_1 = (const float*)d_in[11];
    const float* b1_1 = (const float*)d_in[12];
    const float* w2_1 = (const float*)d_in[13];
    const float* w3_1 = (const float*)d_in[14];
    const float* b3_1 = (const float*)d_in[15];
    const float* w1_2 = (const float*)d_in[16];
    const float* b1_2 = (const float*)d_in[17];
    const float* w2_2 = (const float*)d_in[18];
    const float* w3_2 = (const float*)d_in[19];
    const float* b3_2 = (const float*)d_in[20];
    float* out = (float*)d_out;

    char* ws = (char*)d_ws;
    float* ew      = (float*)(ws);                 // E floats   (3.2 MB)
    float* c       = (float*)(ws + 3200000);       // N floats
    int*   deg     = (int*)  (ws + 3400000);       // N ints (contiguous after c)
    int*   cursor  = (int*)  (ws + 3600000);       // N ints
    int*   rowptr  = (int*)  (ws + 3800000);       // N+1 ints
    int*   csr_src = (int*)  (ws + 4000128);       // E ints     (3.2 MB)
    float* csr_w   = (float*)(ws + 7200128);       // E floats   (3.2 MB)
    float* s       = (float*)(ws + 10400128);      // N*128 floats (25.6 MB)
    float* hA      = (float*)(ws + 36000128);      // N*64 floats  (12.8 MB)
    float* hB      = (float*)(ws + 48800128);      // N*128 floats (25.6 MB)
    // scan scratch lives at head of s (free until gathers run)
    int* blk_sums = (int*)s;
    int* blk_offs = (int*)s + 128;

    // c and deg are contiguous: one memset
    hipMemsetAsync(c, 0, 2 * N_NODES * sizeof(float), stream);

    ew_deg_kernel<<<(N_EDGES + 255) / 256, 256, 0, stream>>>(ea, wfc, bfc, ei, ew, c, deg);
    scan1_kernel<<<SCAN_NB, 256, 0, stream>>>(deg, rowptr, blk_sums);
    scan2_kernel<<<1, 128, 0, stream>>>(blk_sums, blk_offs, rowptr);
    scan3_kernel<<<(N_NODES + 255) / 256, 256, 0, stream>>>(rowptr, blk_offs, cursor);
    place_kernel<<<(N_EDGES + 255) / 256, 256, 0, stream>>>(ei, ew, cursor, csr_src, csr_w);

    dim3 g64((N_NODES + 63) / 64, 1);
    dim3 g128((N_NODES + 63) / 64, 2);

    // layer 0: 64 -> 64, in x, out hA
    gather_kernel<64><<<(N_NODES * 16 + 255) / 256, 256, 0, stream>>>(x, rowptr, csr_src, csr_w, s);
    leconv_gemm<64, 64><<<g64, 256, 0, stream>>>(x, s, c, w1_0, b1_0, w2_0, w3_0, b3_0, hA);

    // layer 1: 64 -> 128, in hA, out hB
    gather_kernel<64><<<(N_NODES * 16 + 255) / 256, 256, 0, stream>>>(hA, rowptr, csr_src, csr_w, s);
    leconv_gemm<64, 128><<<g128, 256, 0, stream>>>(hA, s, c, w1_1, b1_1, w2_1, w3_1, b3_1, hB);

    // layer 2: 128 -> 64, in hB, out hA
    gather_kernel<128><<<(N_NODES * 32 + 255) / 256, 256, 0, stream>>>(hB, rowptr, csr_src, csr_w, s);
    leconv_gemm<128, 64><<<g64, 256, 0, stream>>>(hB, s, c, w1_2, b1_2, w2_2, w3_2, b3_2, hA);

    // global max pool
    pool_kernel<<<NUM_GRAPHS_, 256, 0, stream>>>(hA, batch, out);
}

// Round 4
// 457.279 us; speedup vs baseline: 6.5063x; 1.1666x over previous
//
#include <hip/hip_runtime.h>
#include <math.h>

#define N_NODES 50000
#define N_EDGES 800000
#define NUM_GRAPHS_ 128
#define SCAN_NB 98  // ceil(50000/512)

__device__ __forceinline__ float elu_f(float v) {
    return v > 0.f ? v : (__expf(v) - 1.f);
}

// ---------------------------------------------------------------------------
// ew[e] = edge_attr[e,:16] . w_fc1 + b_fc1 ;  deg[dst] += 1
// (c is NOT accumulated here anymore — layer-0 gather computes it for free)
// ---------------------------------------------------------------------------
__global__ void ew_deg_kernel(const float* __restrict__ edge_attr,
                              const float* __restrict__ w_fc1,
                              const float* __restrict__ b_fc1,
                              const int* __restrict__ edge_index,
                              float* __restrict__ ew,
                              int* __restrict__ deg) {
    int e = blockIdx.x * blockDim.x + threadIdx.x;
    if (e >= N_EDGES) return;
    const float4* ea = (const float4*)(edge_attr + (size_t)e * 16);
    const float4* wf = (const float4*)w_fc1;
    float acc = b_fc1[0];
#pragma unroll
    for (int i = 0; i < 4; i++) {
        float4 a = ea[i], w = wf[i];
        acc += a.x * w.x + a.y * w.y + a.z * w.z + a.w * w.w;
    }
    ew[e] = acc;
    atomicAdd(&deg[edge_index[N_EDGES + e]], 1);
}

// ---------------------------------------------------------------------------
// Hierarchical exclusive scan of deg[N] -> rowptr[N+1], cursor[N]
// ---------------------------------------------------------------------------
__global__ __launch_bounds__(256) void scan1_kernel(const int* __restrict__ deg,
                                                    int* __restrict__ rowptr,
                                                    int* __restrict__ blk_sums) {
    __shared__ int sh[256];
    const int t = threadIdx.x;
    const int base = blockIdx.x * 512;
    const int i0 = base + 2 * t, i1 = i0 + 1;
    const int d0 = (i0 < N_NODES) ? deg[i0] : 0;
    const int d1 = (i1 < N_NODES) ? deg[i1] : 0;
    const int pair = d0 + d1;
    int v = pair;
    sh[t] = v;
    __syncthreads();
#pragma unroll
    for (int off = 1; off < 256; off <<= 1) {
        int add = (t >= off) ? sh[t - off] : 0;
        __syncthreads();
        v += add;
        sh[t] = v;
        __syncthreads();
    }
    const int excl = v - pair;
    if (i0 < N_NODES) rowptr[i0] = excl;
    if (i1 < N_NODES) rowptr[i1] = excl + d0;
    if (t == 255) blk_sums[blockIdx.x] = v;
}

__global__ __launch_bounds__(128) void scan2_kernel(const int* __restrict__ blk_sums,
                                                    int* __restrict__ blk_offs,
                                                    int* __restrict__ rowptr) {
    __shared__ int sh[128];
    const int t = threadIdx.x;
    const int orig = (t < SCAN_NB) ? blk_sums[t] : 0;
    int v = orig;
    sh[t] = v;
    __syncthreads();
#pragma unroll
    for (int off = 1; off < 128; off <<= 1) {
        int add = (t >= off) ? sh[t - off] : 0;
        __syncthreads();
        v += add;
        sh[t] = v;
        __syncthreads();
    }
    if (t < SCAN_NB) blk_offs[t] = v - orig;
    if (t == 127) rowptr[N_NODES] = v;
}

__global__ void scan3_kernel(int* __restrict__ rowptr,
                             const int* __restrict__ blk_offs,
                             int* __restrict__ cursor) {
    int i = blockIdx.x * blockDim.x + threadIdx.x;
    if (i >= N_NODES) return;
    int r = rowptr[i] + blk_offs[i >> 9];
    rowptr[i] = r;
    cursor[i] = r;
}

// ---------------------------------------------------------------------------
// CSR placement with PACKED entries: csr[pos] = {src, bits(w)}
// ---------------------------------------------------------------------------
__global__ void place_kernel(const int* __restrict__ edge_index,
                             const float* __restrict__ ew,
                             int* __restrict__ cursor,
                             int2* __restrict__ csr) {
    int e = blockIdx.x * blockDim.x + threadIdx.x;
    if (e >= N_EDGES) return;
    int dst = edge_index[N_EDGES + e];
    int pos = atomicAdd(&cursor[dst], 1);
    int2 ent;
    ent.x = edge_index[e];
    ent.y = __float_as_int(ew[e]);
    csr[pos] = ent;
}

// ---------------------------------------------------------------------------
// Gather aggregation, one WAVE (64 lanes) per node.
// Lanes = EG edge-groups x CG col-groups (float4 each). 2x unrolled
// => 2*EG independent load chains per node. shfl_xor reduce across EG.
// Layer 0 additionally emits c[node] = sum of w over the row.
// ---------------------------------------------------------------------------
template <int DIN, bool WRITE_C>
__global__ __launch_bounds__(256) void gather_kernel(
    const float* __restrict__ x, const int* __restrict__ rowptr,
    const int2* __restrict__ csr, float* __restrict__ s,
    float* __restrict__ c) {
    constexpr int CG = DIN / 4;   // 16 (DIN=64) or 32 (DIN=128)
    constexpr int EG = 64 / CG;   // 4 or 2
    const int gid = blockIdx.x * 256 + threadIdx.x;
    const int node = gid >> 6;
    if (node >= N_NODES) return;
    const int lane = threadIdx.x & 63;
    const int cg = lane & (CG - 1);
    const int eg = lane / CG;
    const int beg = rowptr[node];
    const int end = rowptr[node + 1];
    const float4* x4 = (const float4*)x;

    float4 a0 = make_float4(0.f, 0.f, 0.f, 0.f);
    float4 a1 = make_float4(0.f, 0.f, 0.f, 0.f);
    float wsum = 0.f;

    int p = beg + eg;
    for (; p + EG < end; p += 2 * EG) {
        int2 e0 = csr[p];
        int2 e1 = csr[p + EG];
        float w0 = __int_as_float(e0.y);
        float w1 = __int_as_float(e1.y);
        float4 v0 = x4[(size_t)e0.x * CG + cg];
        float4 v1 = x4[(size_t)e1.x * CG + cg];
        a0.x += w0 * v0.x; a0.y += w0 * v0.y; a0.z += w0 * v0.z; a0.w += w0 * v0.w;
        a1.x += w1 * v1.x; a1.y += w1 * v1.y; a1.z += w1 * v1.z; a1.w += w1 * v1.w;
        wsum += w0 + w1;
    }
    if (p < end) {
        int2 e0 = csr[p];
        float w0 = __int_as_float(e0.y);
        float4 v0 = x4[(size_t)e0.x * CG + cg];
        a0.x += w0 * v0.x; a0.y += w0 * v0.y; a0.z += w0 * v0.z; a0.w += w0 * v0.w;
        wsum += w0;
    }
    a0.x += a1.x; a0.y += a1.y; a0.z += a1.z; a0.w += a1.w;

    // reduce across edge-groups (xor masks >= CG keep cg fixed)
#pragma unroll
    for (int off = 32; off >= CG; off >>= 1) {
        a0.x += __shfl_xor(a0.x, off);
        a0.y += __shfl_xor(a0.y, off);
        a0.z += __shfl_xor(a0.z, off);
        a0.w += __shfl_xor(a0.w, off);
        if (WRITE_C) wsum += __shfl_xor(wsum, off);
    }
    if (lane < CG) ((float4*)s)[(size_t)node * CG + cg] = a0;
    if (WRITE_C && lane == 0) c[node] = wsum;
}

// ---------------------------------------------------------------------------
// xout = elu( [x | s | c*x] @ [w3 ; w1 ; -w2] + b3 + c*b1 )
// ---------------------------------------------------------------------------
template <int DIN, int DOUT>
__global__ __launch_bounds__(256) void leconv_gemm(
    const float* __restrict__ xin, const float* __restrict__ s,
    const float* __restrict__ c,
    const float* __restrict__ w1, const float* __restrict__ b1,
    const float* __restrict__ w2, const float* __restrict__ w3,
    const float* __restrict__ b3, float* __restrict__ xout) {
    constexpr int K = 3 * DIN;
    constexpr int BM = 64, BN = 64, BK = 16;
    __shared__ float As[BK][BM];
    __shared__ float Bs[BK][BN];
    const int tid = threadIdx.x;
    const int row0 = blockIdx.x * BM;
    const int col0 = blockIdx.y * BN;

    const int am = tid >> 2;
    const int akg = tid & 3;
    const int bk = tid >> 4;
    const int bcg = tid & 15;
    const int tm = tid >> 4;
    const int tn = tid & 15;

    const int arow = row0 + am;
    const bool arow_ok = arow < N_NODES;
    const float crow_a = arow_ok ? c[arow] : 0.f;

    float acc[4][4] = {};

    for (int k0 = 0; k0 < K; k0 += BK) {
        const int region = k0 / DIN;
        float4 av = make_float4(0.f, 0.f, 0.f, 0.f);
        if (arow_ok) {
            const int koff = k0 - region * DIN + akg * 4;
            const float* srcp = (region == 1) ? (s + (size_t)arow * DIN + koff)
                                              : (xin + (size_t)arow * DIN + koff);
            av = *(const float4*)srcp;
            if (region == 2) {
                av.x *= crow_a; av.y *= crow_a; av.z *= crow_a; av.w *= crow_a;
            }
        }
        const int kboff = (k0 - region * DIN) + bk;
        const float* wsrc = (region == 0) ? w3 : (region == 1 ? w1 : w2);
        float4 bv = *(const float4*)(wsrc + (size_t)kboff * DOUT + col0 + bcg * 4);
        if (region == 2) { bv.x = -bv.x; bv.y = -bv.y; bv.z = -bv.z; bv.w = -bv.w; }

        __syncthreads();
        As[akg * 4 + 0][am] = av.x;
        As[akg * 4 + 1][am] = av.y;
        As[akg * 4 + 2][am] = av.z;
        As[akg * 4 + 3][am] = av.w;
        *(float4*)&Bs[bk][bcg * 4] = bv;
        __syncthreads();

#pragma unroll
        for (int kk = 0; kk < BK; kk++) {
            float4 a4 = *(const float4*)&As[kk][tm * 4];
            float4 b4 = *(const float4*)&Bs[kk][tn * 4];
            float ar[4] = {a4.x, a4.y, a4.z, a4.w};
            float br[4] = {b4.x, b4.y, b4.z, b4.w};
#pragma unroll
            for (int i = 0; i < 4; i++)
#pragma unroll
                for (int j = 0; j < 4; j++) acc[i][j] += ar[i] * br[j];
        }
    }

#pragma unroll
    for (int i = 0; i < 4; i++) {
        const int row = row0 + tm * 4 + i;
        if (row >= N_NODES) break;
        const float cr = c[row];
        const int col = col0 + tn * 4;
        float4 o;
        o.x = elu_f(acc[i][0] + b3[col + 0] + cr * b1[col + 0]);
        o.y = elu_f(acc[i][1] + b3[col + 1] + cr * b1[col + 1]);
        o.z = elu_f(acc[i][2] + b3[col + 2] + cr * b1[col + 2]);
        o.w = elu_f(acc[i][3] + b3[col + 3] + cr * b1[col + 3]);
        *(float4*)(xout + (size_t)row * DOUT + col) = o;
    }
}

// ---------------------------------------------------------------------------
// out[g, :] = max over nodes of graph g of h[:, :64]; batch is sorted.
// ---------------------------------------------------------------------------
__global__ void pool_kernel(const float* __restrict__ h,
                            const int* __restrict__ batch,
                            float* __restrict__ out) {
    const int g = blockIdx.x;
    const int tid = threadIdx.x;
    int lo = 0, hi = N_NODES;
    while (lo < hi) { int mid = (lo + hi) >> 1; if (batch[mid] < g) lo = mid + 1; else hi = mid; }
    const int beg = lo;
    lo = beg; hi = N_NODES;
    while (lo < hi) { int mid = (lo + hi) >> 1; if (batch[mid] < g + 1) lo = mid + 1; else hi = mid; }
    const int end = lo;

    __shared__ float red[256];
    const int col = tid & 63;
    const int rg = tid >> 6;
    float m = -3.0e38f;
    for (int r = beg + rg; r < end; r += 4) m = fmaxf(m, h[(size_t)r * 64 + col]);
    red[tid] = m;
    __syncthreads();
    if (tid < 64) {
        m = fmaxf(fmaxf(red[tid], red[tid + 64]), fmaxf(red[tid + 128], red[tid + 192]));
        out[g * 64 + tid] = m;
    }
}

extern "C" void kernel_launch(void* const* d_in, const int* in_sizes, int n_in,
                              void* d_out, int out_size, void* d_ws, size_t ws_size,
                              hipStream_t stream) {
    const float* x = (const float*)d_in[0];
    const int* ei = (const int*)d_in[1];
    const float* ea = (const float*)d_in[2];
    const int* batch = (const int*)d_in[3];
    const float* wfc = (const float*)d_in[4];
    const float* bfc = (const float*)d_in[5];
    const float* w1_0 = (const float*)d_in[6];
    const float* b1_0 = (const float*)d_in[7];
    const float* w2_0 = (const float*)d_in[8];
    const float* w3_0 = (const float*)d_in[9];
    const float* b3_0 = (const float*)d_in[10];
    const float* w1_1 = (const float*)d_in[11];
    const float* b1_1 = (const float*)d_in[12];
    const float* w2_1 = (const float*)d_in[13];
    const float* w3_1 = (const float*)d_in[14];
    const float* b3_1 = (const float*)d_in[15];
    const float* w1_2 = (const float*)d_in[16];
    const float* b1_2 = (const float*)d_in[17];
    const float* w2_2 = (const float*)d_in[18];
    const float* w3_2 = (const float*)d_in[19];
    const float* b3_2 = (const float*)d_in[20];
    float* out = (float*)d_out;

    char* ws = (char*)d_ws;
    float* ew      = (float*)(ws);                 // E floats   (3.2 MB)
    float* c       = (float*)(ws + 3200000);       // N floats (written by gather0)
    int*   deg     = (int*)  (ws + 3400000);       // N ints
    int*   cursor  = (int*)  (ws + 3600000);       // N ints
    int*   rowptr  = (int*)  (ws + 3800000);       // N+1 ints
    int2*  csr     = (int2*) (ws + 4000128);       // E int2     (6.4 MB)
    float* s       = (float*)(ws + 10400128);      // N*128 floats (25.6 MB)
    float* hA      = (float*)(ws + 36000128);      // N*64 floats  (12.8 MB)
    float* hB      = (float*)(ws + 48800128);      // N*128 floats (25.6 MB)
    int* blk_sums = (int*)s;       // scan scratch, free until gathers run
    int* blk_offs = (int*)s + 128;

    hipMemsetAsync(deg, 0, N_NODES * sizeof(int), stream);

    ew_deg_kernel<<<(N_EDGES + 255) / 256, 256, 0, stream>>>(ea, wfc, bfc, ei, ew, deg);
    scan1_kernel<<<SCAN_NB, 256, 0, stream>>>(deg, rowptr, blk_sums);
    scan2_kernel<<<1, 128, 0, stream>>>(blk_sums, blk_offs, rowptr);
    scan3_kernel<<<(N_NODES + 255) / 256, 256, 0, stream>>>(rowptr, blk_offs, cursor);
    place_kernel<<<(N_EDGES + 255) / 256, 256, 0, stream>>>(ei, ew, cursor, csr);

    dim3 g64((N_NODES + 63) / 64, 1);
    dim3 g128((N_NODES + 63) / 64, 2);
    const int GBLK = (N_NODES * 64 + 255) / 256;  // one wave per node

    // layer 0: 64 -> 64, in x, out hA (also emits c)
    gather_kernel<64, true><<<GBLK, 256, 0, stream>>>(x, rowptr, csr, s, c);
    leconv_gemm<64, 64><<<g64, 256, 0, stream>>>(x, s, c, w1_0, b1_0, w2_0, w3_0, b3_0, hA);

    // layer 1: 64 -> 128, in hA, out hB
    gather_kernel<64, false><<<GBLK, 256, 0, stream>>>(hA, rowptr, csr, s, c);
    leconv_gemm<64, 128><<<g128, 256, 0, stream>>>(hA, s, c, w1_1, b1_1, w2_1, w3_1, b3_1, hB);

    // layer 2: 128 -> 64, in hB, out hA
    gather_kernel<128, false><<<GBLK, 256, 0, stream>>>(hB, rowptr, csr, s, c);
    leconv_gemm<128, 64><<<g64, 256, 0, stream>>>(hB, s, c, w1_2, b1_2, w2_2, w3_2, b3_2, hA);

    // global max pool
    pool_kernel<<<NUM_GRAPHS_, 256, 0, stream>>>(hA, batch, out);
}